// Round 2
// baseline (448.960 us; speedup 1.0000x reference)
//
#include <hip/hip_runtime.h>
#include <hip/hip_bf16.h>

typedef unsigned short ushort_t;
typedef unsigned int uint_t;

typedef __attribute__((ext_vector_type(8))) short short8;
typedef __attribute__((ext_vector_type(4))) float f32x4;

#define BATCH 512
#define DK    512
#define CTOT  100000
#define BN    32
#define THRESH_C (-0.8775825618903728f)   // cos(pi - 0.5)
#define MM_C     (0.2397127693021015f)    // sin(0.5)*0.5

// round-to-nearest-even fp32 -> bf16
static __device__ __forceinline__ ushort_t f2bf(float f) {
    union { float f; uint_t u; } v; v.f = f;
    return (ushort_t)((v.u + 0x7FFFu + ((v.u >> 16) & 1u)) >> 16);
}

// ---------------------------------------------------------------------------
// Prep: normalize x rows -> bf16 stored in MFMA-A-fragment-major order:
//   exbF[row_block(32)][ko(16)][lane(64)*8 elems]
//   element (b,k): row_block=b>>4, ko=k>>5, lane=(k>>3&3)*16+(b&15), j=k&7
// Also computes fp32-exact target[b] from cos_lb.
// grid = 512 blocks (one per batch row), 256 threads.
// ---------------------------------------------------------------------------
__global__ __launch_bounds__(256) void arc_prep(
    const float* __restrict__ x, const int* __restrict__ label,
    const float* __restrict__ w, float* __restrict__ target,
    ushort_t* __restrict__ exbF)
{
    const int b = blockIdx.x;
    const int t = threadIdx.x;
    __shared__ float red[8];

    const float2 xv = ((const float2*)(x + (size_t)b * DK))[t];
    float ss = xv.x * xv.x + xv.y * xv.y;
    #pragma unroll
    for (int o = 32; o; o >>= 1) ss += __shfl_xor(ss, o);
    if ((t & 63) == 0) red[t >> 6] = ss;
    __syncthreads();
    const float ssx = red[0] + red[1] + red[2] + red[3];
    const float rnx = 1.0f / sqrtf(ssx);

    {
        const int k = 2 * t;
        const int ko = k >> 5;
        const int qk = (k >> 3) & 3;
        const int kj = k & 7;                       // even
        const size_t F = (size_t)(b >> 4) * 8192 + (size_t)ko * 512
                       + (size_t)qk * 128 + (size_t)(b & 15) * 8 + kj;
        ushort2 e;
        e.x = f2bf(xv.x * rnx);
        e.y = f2bf(xv.y * rnx);
        *(ushort2*)(exbF + F) = e;
    }

    const int lb = label[b];
    const float2 wv = ((const float2*)(w + (size_t)lb * DK))[t];
    float ssw = wv.x * wv.x + wv.y * wv.y;
    float dot = xv.x * wv.x + xv.y * wv.y;
    #pragma unroll
    for (int o = 32; o; o >>= 1) { ssw += __shfl_xor(ssw, o); dot += __shfl_xor(dot, o); }
    __syncthreads();                 // guard red[] reuse
    if ((t & 63) == 0) { red[t >> 6] = ssw; red[4 + (t >> 6)] = dot; }
    __syncthreads();
    if (t == 0) {
        const float sw = red[0] + red[1] + red[2] + red[3];
        const float dt = red[4] + red[5] + red[6] + red[7];
        float cl = dt * rnx / sqrtf(sw);
        cl = fminf(fmaxf(cl, -1.0f), 1.0f);
        const float tg = (cl > THRESH_C) ? cosf(acosf(cl) + 0.5f) : (cl - MM_C);
        target[b] = tg;
    }
}

// ---------------------------------------------------------------------------
// W convert: one streaming pass fp32 W -> bf16 fragment-major wbF (same
// per-16-row-block fragment formula as exbF) + per-class 1/sqrt(sumsq) fp32.
// This hoists the per-tile staging+conversion work (previously redone by
// every arc_main block inside its latency chain) into one coalesced pass.
// grid = 6250 blocks (16 class rows each), 256 threads (16 per row).
// ---------------------------------------------------------------------------
__global__ __launch_bounds__(256) void arc_wcvt(
    const float* __restrict__ w, ushort_t* __restrict__ wbF,
    float* __restrict__ rnw)
{
    const int rb  = blockIdx.x;        // row-block 0..6249
    const int t   = threadIdx.x;
    const int r   = t >> 4;            // 0..15 local row
    const int c16 = t & 15;
    const int row = rb * 16 + r;
    const float* wrow = w + (size_t)row * DK;
    ushort_t* fbase = wbF + (size_t)rb * 8192 + (size_t)r * 8;

    float ss = 0.0f;
    #pragma unroll
    for (int i = 0; i < 8; ++i) {
        const int c = i * 64 + c16 * 4;            // 16 lanes -> 256B contiguous
        const float4 q = *(const float4*)(wrow + c);
        ss += q.x * q.x + q.y * q.y + q.z * q.z + q.w * q.w;
        ushort4 e;
        e.x = f2bf(q.x); e.y = f2bf(q.y); e.z = f2bf(q.z); e.w = f2bf(q.w);
        const int ko = c >> 5;
        const int qk = (c >> 3) & 3;
        const int j0 = c & 7;                      // 0 or 4
        *(ushort4*)(fbase + ko * 512 + qk * 128 + j0) = e;
    }
    // 16 lanes of one row are contiguous within the wave
    ss += __shfl_xor(ss, 1);
    ss += __shfl_xor(ss, 2);
    ss += __shfl_xor(ss, 4);
    ss += __shfl_xor(ss, 8);
    if (c16 == 0) rnw[row] = 1.0f / sqrtf(ss);
}

// ---------------------------------------------------------------------------
// Main (fast path): pure-dataflow bf16 GEMM + epilogue. No LDS, no barriers,
// no conversion. Per wave: 64 batch rows x 32 classes; 16 K-steps of
// {4 A-frag + 2 B-frag loads, 16B/lane fully coalesced, L2/L3-hot} + 8 MFMA.
// Output stores are nontemporal so the 205MB stream doesn't evict wbF/L3.
// grid = 3125 tiles x 2 halves, 256 threads (4 independent waves).
// ---------------------------------------------------------------------------
__global__ __launch_bounds__(256, 6) void arc_main_ff(
    const ushort_t* __restrict__ exbF, const ushort_t* __restrict__ wbF,
    const float* __restrict__ rnw, const int* __restrict__ label,
    const float* __restrict__ target, float* __restrict__ out)
{
    const int t    = threadIdx.x;
    const int lane = t & 63;
    const int tile = blockIdx.x >> 1;
    const int rg   = (t >> 6) + 4 * (blockIdx.x & 1);   // 0..7 row-group
    const int c0   = tile * BN;
    const int colq = lane & 15;
    const int qk   = lane >> 4;

    const ushort_t* abase = exbF + (size_t)(rg * 4) * 8192 + (size_t)lane * 8;
    const ushort_t* bbase = wbF + (size_t)(tile * 2) * 8192 + (size_t)lane * 8;

    f32x4 acc[4][2];
    #pragma unroll
    for (int i = 0; i < 4; ++i)
        #pragma unroll
        for (int j = 0; j < 2; ++j)
            acc[i][j] = (f32x4){0.f, 0.f, 0.f, 0.f};

    #pragma unroll 4
    for (int ko = 0; ko < 16; ++ko) {
        const short8 b0 = *(const short8*)(bbase + ko * 512);
        const short8 b1 = *(const short8*)(bbase + 8192 + ko * 512);
        #pragma unroll
        for (int mt = 0; mt < 4; ++mt) {
            const short8 afr = *(const short8*)(abase + (size_t)mt * 8192 + ko * 512);
            acc[mt][0] = __builtin_amdgcn_mfma_f32_16x16x32_bf16(afr, b0, acc[mt][0], 0, 0, 0);
            acc[mt][1] = __builtin_amdgcn_mfma_f32_16x16x32_bf16(afr, b1, acc[mt][1], 0, 0, 0);
        }
    }

    const float rn0 = rnw[c0 + colq];
    const float rn1 = rnw[c0 + 16 + colq];

    const int m0 = rg * 64;
    #pragma unroll
    for (int mt = 0; mt < 4; ++mt) {
        #pragma unroll
        for (int rr = 0; rr < 4; ++rr) {
            const int row = m0 + mt * 16 + qk * 4 + rr;
            const float tg = target[row];
            const int   lb = label[row];
            float* orow = out + (size_t)row * CTOT + c0;
            {
                const float cosv = acc[mt][0][rr] * rn0;
                const float d  = cosv - tg;
                const float ts = 1.2f * __expf(d * d * -0.5f);
                const float v  = ((c0 + colq) == lb) ? 64.0f * tg
                                                     : 64.0f * (ts * cosv + ts - 1.0f);
                __builtin_nontemporal_store(v, &orow[colq]);
            }
            {
                const float cosv = acc[mt][1][rr] * rn1;
                const float d  = cosv - tg;
                const float ts = 1.2f * __expf(d * d * -0.5f);
                const float v  = ((c0 + 16 + colq) == lb) ? 64.0f * tg
                                                          : 64.0f * (ts * cosv + ts - 1.0f);
                __builtin_nontemporal_store(v, &orow[16 + colq]);
            }
        }
    }
}

// ---------------------------------------------------------------------------
// Fallback (verified round-1 kernel) used if workspace can't hold wbF.
// ---------------------------------------------------------------------------
__global__ __launch_bounds__(512, 8) void arc_main_lds(
    const ushort_t* __restrict__ exbF, const float* __restrict__ w,
    const int* __restrict__ label, const float* __restrict__ target,
    float* __restrict__ out)
{
    __shared__ ushort_t Bs[BN * DK];   // 32 KB

    const int t    = threadIdx.x;
    const int lane = t & 63;
    const int wid  = t >> 6;
    const int c0   = blockIdx.x * BN;

    const int br  = t >> 4;
    const int bj  = t & 15;
    const float* wrow = w + (size_t)(c0 + br) * DK;
    const int s3 = br & 7;
    float bsq = 0.0f;
    #pragma unroll
    for (int i = 0; i < 8; ++i) {
        const int c = i * 64 + bj * 4;
        const float4 q = *(const float4*)(wrow + c);
        bsq += q.x * q.x + q.y * q.y + q.z * q.z + q.w * q.w;
        uint2 p;
        p.x = (uint_t)f2bf(q.x) | ((uint_t)f2bf(q.y) << 16);
        p.y = (uint_t)f2bf(q.z) | ((uint_t)f2bf(q.w) << 16);
        const int k16 = c >> 3;
        const int sw  = k16 ^ s3;
        *(uint2*)&Bs[br * DK + sw * 8 + (bj & 1) * 4] = p;
    }
    bsq += __shfl_xor(bsq, 1);
    bsq += __shfl_xor(bsq, 2);
    bsq += __shfl_xor(bsq, 4);
    bsq += __shfl_xor(bsq, 8);
    __syncthreads();

    const int m0   = wid * 64;
    const int colq = lane & 15;
    const int qk   = lane >> 4;
    const int bs3  = colq & 7;
    const ushort_t* abase = exbF + (size_t)(wid * 4) * 8192 + (size_t)lane * 8;

    f32x4 acc[4][2];
    #pragma unroll
    for (int i = 0; i < 4; ++i)
        #pragma unroll
        for (int j = 0; j < 2; ++j)
            acc[i][j] = (f32x4){0.f, 0.f, 0.f, 0.f};

    #pragma unroll 2
    for (int ko = 0; ko < 16; ++ko) {
        short8 bfr[2];
        #pragma unroll
        for (int nt = 0; nt < 2; ++nt) {
            const int idx = (nt * 16 + colq) * DK + (((ko << 2) | qk) ^ bs3) * 8;
            bfr[nt] = *(const short8*)&Bs[idx];
        }
        #pragma unroll
        for (int mt = 0; mt < 4; ++mt) {
            const short8 afr = *(const short8*)(abase + (size_t)mt * 8192 + ko * 512);
            acc[mt][0] = __builtin_amdgcn_mfma_f32_16x16x32_bf16(afr, bfr[0], acc[mt][0], 0, 0, 0);
            acc[mt][1] = __builtin_amdgcn_mfma_f32_16x16x32_bf16(afr, bfr[1], acc[mt][1], 0, 0, 0);
        }
    }

    __syncthreads();
    if (bj == 0) ((float*)Bs)[br] = 1.0f / sqrtf(bsq);
    __syncthreads();
    float rn[2];
    rn[0] = ((float*)Bs)[colq];
    rn[1] = ((float*)Bs)[16 + colq];

    #pragma unroll
    for (int mt = 0; mt < 4; ++mt) {
        #pragma unroll
        for (int rr = 0; rr < 4; ++rr) {
            const int row = m0 + mt * 16 + qk * 4 + rr;
            const float tg = target[row];
            const int   lb = label[row];
            float* orow = out + (size_t)row * CTOT + c0;
            #pragma unroll
            for (int nt = 0; nt < 2; ++nt) {
                const int cc = c0 + nt * 16 + colq;
                const float cosv = acc[mt][nt][rr] * rn[nt];
                const float d  = cosv - tg;
                const float ts = 1.2f * __expf(d * d * -0.5f);
                const float v  = (cc == lb) ? 64.0f * tg
                                            : 64.0f * (ts * cosv + ts - 1.0f);
                orow[nt * 16 + colq] = v;
            }
        }
    }
}

extern "C" void kernel_launch(void* const* d_in, const int* in_sizes, int n_in,
                              void* d_out, int out_size, void* d_ws, size_t ws_size,
                              hipStream_t stream) {
    const float* x     = (const float*)d_in[0];
    const int*   label = (const int*)d_in[1];
    const float* w     = (const float*)d_in[2];
    float* out = (float*)d_out;

    // workspace layout
    float*    target = (float*)d_ws;                          // 2 KB
    ushort_t* exbF   = (ushort_t*)((char*)d_ws + 2048);       // 512 KB
    float*    rnw    = (float*)((char*)d_ws + 526336);        // 400 KB
    ushort_t* wbF    = (ushort_t*)((char*)d_ws + 935936);     // 102.4 MB
    const size_t WS_NEED = 935936 + (size_t)CTOT * DK * 2;    // 103,335,936

    arc_prep<<<512, 256, 0, stream>>>(x, label, w, target, exbF);

    if (ws_size >= WS_NEED) {
        arc_wcvt<<<CTOT / 16, 256, 0, stream>>>(w, wbF, rnw);
        arc_main_ff<<<(CTOT / BN) * 2, 256, 0, stream>>>(exbF, wbF, rnw, label, target, out);
    } else {
        arc_main_lds<<<CTOT / BN, 512, 0, stream>>>(exbF, w, label, target, out);
    }
}